// Round 2
// baseline (482.385 us; speedup 1.0000x reference)
//
#include <hip/hip_runtime.h>
#include <hip/hip_bf16.h>
#include <cstdint>

// ---- problem constants ----
#define BB 32
#define NN 1024
#define CC 768
#define MM 64
#define HH 12
#define DD 64

typedef float f4v __attribute__((ext_vector_type(4)));
typedef __bf16 bf8 __attribute__((ext_vector_type(8)));

__device__ __forceinline__ f4v mfma16(bf8 a, bf8 b, f4v c) {
    return __builtin_amdgcn_mfma_f32_16x16x32_bf16(a, b, c, 0, 0, 0);
}
__device__ __forceinline__ __bf16 f2bf(float f) { return (__bf16)f; }

__device__ __forceinline__ void gl2lds16(const void* g, void* lds) {
    __builtin_amdgcn_global_load_lds((const __attribute__((address_space(1))) void*)g,
                                     (__attribute__((address_space(3))) void*)lds, 16, 0, 0);
}

// ---------- weight fp32 -> bf16 ----------
__global__ void k_cvt(const float* __restrict__ in, __bf16* __restrict__ out, int n) {
    int i = blockIdx.x * 256 + threadIdx.x;
    if (i < n) out[i] = f2bf(in[i]);
}

// ---------- K1: c[b,n,m] = sigmoid(x@Wc^T + bc)/N  (stored (b,n,m) bf16) ----------
__global__ __launch_bounds__(256) void k_cluster(const float* __restrict__ x,
        const __bf16* __restrict__ Wc, const float* __restrict__ bc,
        __bf16* __restrict__ cbuf) {
    int n0 = blockIdx.x * 128;
    int b  = blockIdx.y;
    __shared__ __align__(16) __bf16 xs[128 * 32];
    __shared__ __align__(16) __bf16 wcs[64 * 32];
    int t = threadIdx.x, w = t >> 6, l = t & 63, quad = l >> 4, l16 = l & 15;
    f4v acc[2][4];
#pragma unroll
    for (int i = 0; i < 2; i++) for (int j = 0; j < 4; j++) acc[i][j] = (f4v)0.0f;

    for (int k0 = 0; k0 < CC; k0 += 32) {
#pragma unroll
        for (int i = 0; i < 4; i++) {
            int idx = t + 256 * i;
            int row = idx >> 3, kq = idx & 7;
            float4 v4 = *(const float4*)&x[((size_t)b * NN + n0 + row) * CC + k0 + kq * 4];
            __bf16* dst = &xs[row * 32 + kq * 4];
            dst[0] = f2bf(v4.x); dst[1] = f2bf(v4.y); dst[2] = f2bf(v4.z); dst[3] = f2bf(v4.w);
        }
        {
            int row = t >> 2, ch = t & 3;
            *(bf8*)&wcs[row * 32 + ch * 8] = *(const bf8*)&Wc[(size_t)row * CC + k0 + ch * 8];
        }
        __syncthreads();
        bf8 afr[2], bfr[4];
#pragma unroll
        for (int sr = 0; sr < 2; sr++) afr[sr] = *(const bf8*)&xs[(w * 32 + sr * 16 + l16) * 32 + quad * 8];
#pragma unroll
        for (int sc = 0; sc < 4; sc++) bfr[sc] = *(const bf8*)&wcs[(sc * 16 + l16) * 32 + quad * 8];
#pragma unroll
        for (int sr = 0; sr < 2; sr++)
#pragma unroll
            for (int sc = 0; sc < 4; sc++)
                acc[sr][sc] = mfma16(afr[sr], bfr[sc], acc[sr][sc]);
        __syncthreads();
    }
#pragma unroll
    for (int sr = 0; sr < 2; sr++)
#pragma unroll
        for (int sc = 0; sc < 4; sc++) {
            int m = sc * 16 + l16;
            float bias = bc[m];
#pragma unroll
            for (int r = 0; r < 4; r++) {
                int n = n0 + w * 32 + sr * 16 + quad * 4 + r;
                float val = acc[sr][sc][r] + bias;
                val = 1.0f / (1.0f + __expf(-val));
                cbuf[((size_t)b * NN + n) * MM + m] = f2bf(val * (1.0f / 1024.0f));
            }
        }
}

// ---------- K2: z[b,m,c] = sum_n c[b,n,m] * x[b,n,c]   (fp32 out) ----------
#define ZS 40  // padded LDS stride (multiple of 8 for 16B-aligned b128 reads)
__global__ __launch_bounds__(256) void k_z(const float* __restrict__ x,
        const __bf16* __restrict__ cbuf, float* __restrict__ z) {
    int c0 = blockIdx.x * 64;
    int b  = blockIdx.y;
    __shared__ __align__(16) __bf16 cs[64 * ZS];
    __shared__ __align__(16) __bf16 xs[64 * ZS];
    int t = threadIdx.x, w = t >> 6, l = t & 63, quad = l >> 4, l16 = l & 15;
    f4v acc[4];
#pragma unroll
    for (int j = 0; j < 4; j++) acc[j] = (f4v)0.0f;

    for (int n0 = 0; n0 < NN; n0 += 32) {
        {   // A: cs[m][nn] = c[b][n0+nn][m]  (transpose-stage)
            int m = t & 63, nn0 = (t >> 6) * 8;
#pragma unroll
            for (int i = 0; i < 8; i++)
                cs[m * ZS + nn0 + i] = cbuf[((size_t)b * NN + n0 + nn0 + i) * MM + m];
        }
        {   // B: xs[cc][nn] = bf16(x[b][n0+nn][c0+cc])  (transpose-stage)
            int cc = t & 63, nn0 = (t >> 6) * 8;
#pragma unroll
            for (int i = 0; i < 8; i++)
                xs[cc * ZS + nn0 + i] = f2bf(x[((size_t)b * NN + n0 + nn0 + i) * CC + c0 + cc]);
        }
        __syncthreads();
        bf8 afr = *(const bf8*)&cs[(w * 16 + l16) * ZS + quad * 8];
#pragma unroll
        for (int sc = 0; sc < 4; sc++) {
            bf8 bfr = *(const bf8*)&xs[(sc * 16 + l16) * ZS + quad * 8];
            acc[sc] = mfma16(afr, bfr, acc[sc]);
        }
        __syncthreads();
    }
#pragma unroll
    for (int sc = 0; sc < 4; sc++) {
        int cc = c0 + sc * 16 + l16;
#pragma unroll
        for (int r = 0; r < 4; r++) {
            int m = w * 16 + quad * 4 + r;
            z[((size_t)b * MM + m) * CC + cc] = acc[sc][r];
        }
    }
}

// ---------- K2b: L2-normalize rows of z (2048 rows x 768), write bf16 ----------
__global__ __launch_bounds__(256) void k_znorm(const float* __restrict__ z, __bf16* __restrict__ zb) {
    int w = threadIdx.x >> 6, l = threadIdx.x & 63;
    int row = blockIdx.x * 4 + w;
    const float* zr = &z[(size_t)row * CC];
    float v[12]; float ss = 0.f;
#pragma unroll
    for (int i = 0; i < 12; i++) { v[i] = zr[l + i * 64]; ss += v[i] * v[i]; }
#pragma unroll
    for (int off = 32; off; off >>= 1) ss += __shfl_xor(ss, off);
    float s = 1.0f / fmaxf(sqrtf(ss), 1e-12f);
    __bf16* zo = &zb[(size_t)row * CC];
#pragma unroll
    for (int i = 0; i < 12; i++) zo[l + i * 64] = f2bf(v[i] * s);
}

// ---------- K3: k/v = z_n @ W^T + b, stored (b,h,m,d) bf16 ----------
__global__ __launch_bounds__(256) void k_kv(const __bf16* __restrict__ zb,
        const __bf16* __restrict__ W, const float* __restrict__ bias,
        __bf16* __restrict__ out) {
    int ct = blockIdx.x;   // 6 col-tiles of 128
    int b  = blockIdx.y;
    __shared__ __align__(16) __bf16 zs[64 * 32];
    __shared__ __align__(16) __bf16 ws[128 * 32];
    int t = threadIdx.x, w = t >> 6, l = t & 63, quad = l >> 4, l16 = l & 15;
    f4v acc[4][2];
#pragma unroll
    for (int i = 0; i < 4; i++) for (int j = 0; j < 2; j++) acc[i][j] = (f4v)0.0f;
    for (int k0 = 0; k0 < CC; k0 += 32) {
        {
            int row = t >> 2, ch = t & 3;
            *(bf8*)&zs[row * 32 + ch * 8] = *(const bf8*)&zb[((size_t)b * MM + row) * CC + k0 + ch * 8];
        }
#pragma unroll
        for (int i = 0; i < 2; i++) {
            int idx = t + 256 * i, row = idx >> 2, ch = idx & 3;
            *(bf8*)&ws[row * 32 + ch * 8] = *(const bf8*)&W[((size_t)(ct * 128 + row)) * CC + k0 + ch * 8];
        }
        __syncthreads();
        bf8 afr[4], bfr[2];
#pragma unroll
        for (int sr = 0; sr < 4; sr++) afr[sr] = *(const bf8*)&zs[(sr * 16 + l16) * 32 + quad * 8];
#pragma unroll
        for (int sc = 0; sc < 2; sc++) bfr[sc] = *(const bf8*)&ws[(w * 32 + sc * 16 + l16) * 32 + quad * 8];
#pragma unroll
        for (int sr = 0; sr < 4; sr++)
#pragma unroll
            for (int sc = 0; sc < 2; sc++)
                acc[sr][sc] = mfma16(afr[sr], bfr[sc], acc[sr][sc]);
        __syncthreads();
    }
#pragma unroll
    for (int sr = 0; sr < 4; sr++)
#pragma unroll
        for (int sc = 0; sc < 2; sc++) {
            int col = ct * 128 + w * 32 + sc * 16 + l16;
            float bb = bias[col];
            int h = col >> 6, d = col & 63;
#pragma unroll
            for (int r = 0; r < 4; r++) {
                int m = sr * 16 + quad * 4 + r;
                out[(((size_t)b * HH + h) * MM + m) * DD + d] = f2bf(acc[sr][sc][r] + bb);
            }
        }
}

// ---------- K4: fused q-proj + attention -> o (b,n,c) bf16 ----------
#define QS 72  // padded stride (mult of 8)
__global__ __launch_bounds__(256) void k_qattn(const float* __restrict__ x,
        const __bf16* __restrict__ Wq, const float* __restrict__ bq,
        const __bf16* __restrict__ kb, const __bf16* __restrict__ vb,
        __bf16* __restrict__ ob) {
    int n0 = blockIdx.x * 128;
    int h  = blockIdx.y;
    int b  = blockIdx.z;
    __shared__ __align__(16) __bf16 xs[128 * 32];
    __shared__ __align__(16) __bf16 wqs[64 * 32];
    __shared__ __align__(16) __bf16 qs[128 * QS];
    __shared__ __align__(16) __bf16 ps[128 * QS];
    __shared__ __align__(16) __bf16 vts[64 * QS];
    int t = threadIdx.x, w = t >> 6, l = t & 63, quad = l >> 4, l16 = l & 15;

    {   // stage v^T once: vts[d][m] = v[b,h,m,d]  (FIX: cover all 8 d-chunks)
        int m = t & 63;
#pragma unroll
        for (int half = 0; half < 2; half++) {
            int ch = (t >> 6) + half * 4;   // 0..7 across waves+halves
            bf8 vv = *(const bf8*)&vb[(((size_t)b * HH + h) * MM + m) * DD + ch * 8];
#pragma unroll
            for (int i = 0; i < 8; i++) vts[(ch * 8 + i) * QS + m] = vv[i];
        }
    }

    // phase 1: q = x @ Wq_h^T
    f4v acc[2][4];
#pragma unroll
    for (int i = 0; i < 2; i++) for (int j = 0; j < 4; j++) acc[i][j] = (f4v)0.0f;
    for (int k0 = 0; k0 < CC; k0 += 32) {
#pragma unroll
        for (int i = 0; i < 4; i++) {
            int idx = t + 256 * i, row = idx >> 3, kq = idx & 7;
            float4 v4 = *(const float4*)&x[((size_t)b * NN + n0 + row) * CC + k0 + kq * 4];
            __bf16* dst = &xs[row * 32 + kq * 4];
            dst[0] = f2bf(v4.x); dst[1] = f2bf(v4.y); dst[2] = f2bf(v4.z); dst[3] = f2bf(v4.w);
        }
        {
            int row = t >> 2, ch = t & 3;
            *(bf8*)&wqs[row * 32 + ch * 8] = *(const bf8*)&Wq[((size_t)(h * 64 + row)) * CC + k0 + ch * 8];
        }
        __syncthreads();
        bf8 afr[2], bfr[4];
#pragma unroll
        for (int sr = 0; sr < 2; sr++) afr[sr] = *(const bf8*)&xs[(w * 32 + sr * 16 + l16) * 32 + quad * 8];
#pragma unroll
        for (int sc = 0; sc < 4; sc++) bfr[sc] = *(const bf8*)&wqs[(sc * 16 + l16) * 32 + quad * 8];
#pragma unroll
        for (int sr = 0; sr < 2; sr++)
#pragma unroll
            for (int sc = 0; sc < 4; sc++)
                acc[sr][sc] = mfma16(afr[sr], bfr[sc], acc[sr][sc]);
        __syncthreads();
    }
    // q (C-layout regs) -> LDS bf16 (A-layout source)
#pragma unroll
    for (int sr = 0; sr < 2; sr++)
#pragma unroll
        for (int sc = 0; sc < 4; sc++) {
            int col = sc * 16 + l16;
            float bb = bq[h * 64 + col];
#pragma unroll
            for (int r = 0; r < 4; r++) {
                int row = w * 32 + sr * 16 + quad * 4 + r;
                qs[row * QS + col] = f2bf(acc[sr][sc][r] + bb);
            }
        }
    __syncthreads();

    // phase 2: s = q @ k^T (K=64), softmax over m
    f4v sacc[2][4];
#pragma unroll
    for (int i = 0; i < 2; i++) for (int j = 0; j < 4; j++) sacc[i][j] = (f4v)0.0f;
#pragma unroll
    for (int kc = 0; kc < 2; kc++) {
        bf8 afr[2], bfr[4];
#pragma unroll
        for (int sr = 0; sr < 2; sr++)
            afr[sr] = *(const bf8*)&qs[(w * 32 + sr * 16 + l16) * QS + kc * 32 + quad * 8];
#pragma unroll
        for (int sc = 0; sc < 4; sc++)
            bfr[sc] = *(const bf8*)&kb[(((size_t)b * HH + h) * MM + sc * 16 + l16) * DD + kc * 32 + quad * 8];
#pragma unroll
        for (int sr = 0; sr < 2; sr++)
#pragma unroll
            for (int sc = 0; sc < 4; sc++)
                sacc[sr][sc] = mfma16(afr[sr], bfr[sc], sacc[sr][sc]);
    }
#pragma unroll
    for (int sr = 0; sr < 2; sr++) {
#pragma unroll
        for (int r = 0; r < 4; r++) {
            float mx = -1e30f;
#pragma unroll
            for (int sc = 0; sc < 4; sc++) mx = fmaxf(mx, sacc[sr][sc][r] * 0.125f);
#pragma unroll
            for (int off = 1; off < 16; off <<= 1) mx = fmaxf(mx, __shfl_xor(mx, off));
            float e[4]; float sum = 0.f;
#pragma unroll
            for (int sc = 0; sc < 4; sc++) { e[sc] = __expf(sacc[sr][sc][r] * 0.125f - mx); sum += e[sc]; }
#pragma unroll
            for (int off = 1; off < 16; off <<= 1) sum += __shfl_xor(sum, off);
            float inv = 1.0f / sum;
            int row = w * 32 + sr * 16 + quad * 4 + r;
#pragma unroll
            for (int sc = 0; sc < 4; sc++) ps[row * QS + sc * 16 + l16] = f2bf(e[sc] * inv);
        }
    }
    __syncthreads();

    // phase 3: o = p @ v  (K=64 over m)
    f4v oacc[2][4];
#pragma unroll
    for (int i = 0; i < 2; i++) for (int j = 0; j < 4; j++) oacc[i][j] = (f4v)0.0f;
#pragma unroll
    for (int kc = 0; kc < 2; kc++) {
        bf8 afr[2], bfr[4];
#pragma unroll
        for (int sr = 0; sr < 2; sr++)
            afr[sr] = *(const bf8*)&ps[(w * 32 + sr * 16 + l16) * QS + kc * 32 + quad * 8];
#pragma unroll
        for (int sc = 0; sc < 4; sc++)
            bfr[sc] = *(const bf8*)&vts[(sc * 16 + l16) * QS + kc * 32 + quad * 8];
#pragma unroll
        for (int sr = 0; sr < 2; sr++)
#pragma unroll
            for (int sc = 0; sc < 4; sc++)
                oacc[sr][sc] = mfma16(afr[sr], bfr[sc], oacc[sr][sc]);
    }
#pragma unroll
    for (int sr = 0; sr < 2; sr++)
#pragma unroll
        for (int sc = 0; sc < 4; sc++) {
            int d = sc * 16 + l16;
#pragma unroll
            for (int r = 0; r < 4; r++) {
                int row = n0 + w * 32 + sr * 16 + quad * 4 + r;
                ob[((size_t)b * NN + row) * CC + h * 64 + d] = f2bf(oacc[sr][sc][r]);
            }
        }
}

// ---------- K5: out = o @ Wp^T + bp  (128x128 tile, global_load_lds) ----------
__global__ __launch_bounds__(256) void k_oproj(const __bf16* __restrict__ ob,
        const __bf16* __restrict__ Wp, const float* __restrict__ bp,
        float* __restrict__ out) {
    int jt = blockIdx.x;   // 6
    size_t arow0 = (size_t)blockIdx.y * 128;   // 256 row tiles
    __shared__ __align__(16) __bf16 As[128 * 32];
    __shared__ __align__(16) __bf16 Bs[128 * 32];
    int t = threadIdx.x, w = t >> 6, l = t & 63, quad = l >> 4, l16 = l & 15;
    int wr = w & 1, wc = w >> 1;
    f4v acc[4][4];
#pragma unroll
    for (int i = 0; i < 4; i++) for (int j = 0; j < 4; j++) acc[i][j] = (f4v)0.0f;
    for (int k0 = 0; k0 < CC; k0 += 32) {
#pragma unroll
        for (int i = 0; i < 2; i++) {
            int row = i * 64 + w * 16 + (l >> 2), ch = l & 3;
            gl2lds16(&ob[(arow0 + row) * CC + k0 + ch * 8], &As[i * 2048 + w * 512]);
            gl2lds16(&Wp[((size_t)(jt * 128 + row)) * CC + k0 + ch * 8], &Bs[i * 2048 + w * 512]);
        }
        __syncthreads();
        bf8 afr[4], bfr[4];
#pragma unroll
        for (int sr = 0; sr < 4; sr++) afr[sr] = *(const bf8*)&As[(wr * 64 + sr * 16 + l16) * 32 + quad * 8];
#pragma unroll
        for (int sc = 0; sc < 4; sc++) bfr[sc] = *(const bf8*)&Bs[(wc * 64 + sc * 16 + l16) * 32 + quad * 8];
#pragma unroll
        for (int sr = 0; sr < 4; sr++)
#pragma unroll
            for (int sc = 0; sc < 4; sc++)
                acc[sr][sc] = mfma16(afr[sr], bfr[sc], acc[sr][sc]);
        __syncthreads();
    }
#pragma unroll
    for (int sc = 0; sc < 4; sc++) {
        int col = jt * 128 + wc * 64 + sc * 16 + l16;
        float bb = bp[col];
#pragma unroll
        for (int sr = 0; sr < 4; sr++)
#pragma unroll
            for (int r = 0; r < 4; r++) {
                size_t row = arow0 + wr * 64 + sr * 16 + quad * 4 + r;
                out[row * CC + col] = acc[sr][sc][r] + bb;
            }
    }
}

extern "C" void kernel_launch(void* const* d_in, const int* in_sizes, int n_in,
                              void* d_out, int out_size, void* d_ws, size_t ws_size,
                              hipStream_t stream) {
    (void)in_sizes; (void)n_in; (void)out_size; (void)ws_size;
    const float* x  = (const float*)d_in[0];
    const float* Wc = (const float*)d_in[1];
    const float* bc = (const float*)d_in[2];
    const float* Wq = (const float*)d_in[3];
    const float* bq = (const float*)d_in[4];
    const float* Wk = (const float*)d_in[5];
    const float* bk = (const float*)d_in[6];
    const float* Wv = (const float*)d_in[7];
    const float* bv = (const float*)d_in[8];
    const float* Wp = (const float*)d_in[9];
    const float* bp = (const float*)d_in[10];
    float* out = (float*)d_out;

    char* ws = (char*)d_ws;
    size_t off = 0;
    auto alloc = [&](size_t bytes) { void* p = ws + off; off = (off + bytes + 255) & ~(size_t)255; return p; };
    __bf16* wc_b = (__bf16*)alloc((size_t)MM * CC * 2);
    __bf16* wq_b = (__bf16*)alloc((size_t)CC * CC * 2);
    __bf16* wk_b = (__bf16*)alloc((size_t)CC * CC * 2);
    __bf16* wv_b = (__bf16*)alloc((size_t)CC * CC * 2);
    __bf16* wp_b = (__bf16*)alloc((size_t)CC * CC * 2);
    __bf16* c_b  = (__bf16*)alloc((size_t)BB * NN * MM * 2);
    float*  z_f  = (float*) alloc((size_t)BB * MM * CC * 4);
    __bf16* z_b  = (__bf16*)alloc((size_t)BB * MM * CC * 2);
    __bf16* k_b  = (__bf16*)alloc((size_t)BB * HH * MM * DD * 2);
    __bf16* v_b  = (__bf16*)alloc((size_t)BB * HH * MM * DD * 2);
    __bf16* o_b  = (__bf16*)alloc((size_t)BB * NN * CC * 2);

    k_cvt<<<(MM * CC + 255) / 256, 256, 0, stream>>>(Wc, wc_b, MM * CC);
    k_cvt<<<(CC * CC + 255) / 256, 256, 0, stream>>>(Wq, wq_b, CC * CC);
    k_cvt<<<(CC * CC + 255) / 256, 256, 0, stream>>>(Wk, wk_b, CC * CC);
    k_cvt<<<(CC * CC + 255) / 256, 256, 0, stream>>>(Wv, wv_b, CC * CC);
    k_cvt<<<(CC * CC + 255) / 256, 256, 0, stream>>>(Wp, wp_b, CC * CC);

    k_cluster<<<dim3(NN / 128, BB), 256, 0, stream>>>(x, wc_b, bc, c_b);
    k_z<<<dim3(CC / 64, BB), 256, 0, stream>>>(x, c_b, z_f);
    k_znorm<<<(BB * MM) / 4, 256, 0, stream>>>(z_f, z_b);
    k_kv<<<dim3(CC / 128, BB), 256, 0, stream>>>(z_b, wk_b, bk, k_b);
    k_kv<<<dim3(CC / 128, BB), 256, 0, stream>>>(z_b, wv_b, bv, v_b);
    k_qattn<<<dim3(NN / 128, HH, BB), 256, 0, stream>>>(x, wq_b, bq, k_b, v_b, o_b);
    k_oproj<<<dim3(CC / 128, (BB * NN) / 128), 256, 0, stream>>>(o_b, wp_b, bp, out);
}

// Round 3
// 481.145 us; speedup vs baseline: 1.0026x; 1.0026x over previous
//
#include <hip/hip_runtime.h>
#include <hip/hip_bf16.h>
#include <cstdint>

// ---- problem constants ----
#define BB 32
#define NN 1024
#define CC 768
#define MM 64
#define HH 12
#define DD 64

typedef float f4v __attribute__((ext_vector_type(4)));
typedef __bf16 bf8 __attribute__((ext_vector_type(8)));
typedef __bf16 bf4 __attribute__((ext_vector_type(4)));

__device__ __forceinline__ f4v mfma16(bf8 a, bf8 b, f4v c) {
    return __builtin_amdgcn_mfma_f32_16x16x32_bf16(a, b, c, 0, 0, 0);
}
__device__ __forceinline__ __bf16 f2bf(float f) { return (__bf16)f; }

__device__ __forceinline__ void gl2lds16(const void* g, void* lds) {
    __builtin_amdgcn_global_load_lds((const __attribute__((address_space(1))) void*)g,
                                     (__attribute__((address_space(3))) void*)lds, 16, 0, 0);
}

// ---------- weight fp32 -> bf16 (vectorized x4) ----------
__global__ void k_cvt4(const float* __restrict__ in, __bf16* __restrict__ out, int n4) {
    int i = blockIdx.x * 256 + threadIdx.x;
    if (i < n4) {
        float4 v = *(const float4*)&in[i * 4];
        bf4 o; o[0] = f2bf(v.x); o[1] = f2bf(v.y); o[2] = f2bf(v.z); o[3] = f2bf(v.w);
        *(bf4*)&out[i * 4] = o;
    }
}

// ---------- K0: x -> xb (b,n,c) bf16  AND  xt (b,c,n) bf16 (tiled transpose) ----------
#define TS 80  // LDS tile stride (160 B: 16B-aligned rows, bank-rotating)
__global__ __launch_bounds__(256) void k_cvtx(const float* __restrict__ x,
        __bf16* __restrict__ xb, __bf16* __restrict__ xt) {
    int c0 = blockIdx.x * 64, n0 = blockIdx.y * 64, b = blockIdx.z;
    __shared__ __align__(16) __bf16 tile[64 * TS];
    int t = threadIdx.x;
#pragma unroll
    for (int i = 0; i < 4; i++) {
        int idx = t + 256 * i, r = idx >> 4, cq = idx & 15;
        float4 v = *(const float4*)&x[((size_t)(b * NN + n0 + r)) * CC + c0 + cq * 4];
        __bf16* d = &tile[r * TS + cq * 4];
        d[0] = f2bf(v.x); d[1] = f2bf(v.y); d[2] = f2bf(v.z); d[3] = f2bf(v.w);
    }
    __syncthreads();
#pragma unroll
    for (int i = 0; i < 2; i++) {
        int idx = t + 256 * i, r = idx >> 3, ch = idx & 7;
        *(bf8*)&xb[((size_t)(b * NN + n0 + r)) * CC + c0 + ch * 8] = *(const bf8*)&tile[r * TS + ch * 8];
    }
    {
        int c = t & 63, nb = t >> 6;
        bf8 v0, v1;
#pragma unroll
        for (int i = 0; i < 8; i++) { v0[i] = tile[(nb * 16 + i) * TS + c]; v1[i] = tile[(nb * 16 + 8 + i) * TS + c]; }
        size_t base = ((size_t)(b * CC + c0 + c)) * NN + n0 + nb * 16;
        *(bf8*)&xt[base] = v0; *(bf8*)&xt[base + 8] = v1;
    }
}

// ---------- K1: c_bmn[b,m,n] = sigmoid(x@Wc^T + bc)/N   (LDS-free) ----------
__global__ __launch_bounds__(256) void k_cluster(const __bf16* __restrict__ xb,
        const __bf16* __restrict__ Wc, const float* __restrict__ bc,
        __bf16* __restrict__ cbmn) {
    int n0 = blockIdx.x * 128, b = blockIdx.y;
    int t = threadIdx.x, w = t >> 6, l = t & 63, quad = l >> 4, l16 = l & 15;
    f4v acc[2][4];
#pragma unroll
    for (int i = 0; i < 2; i++) for (int j = 0; j < 4; j++) acc[i][j] = (f4v)0.0f;
    for (int k0 = 0; k0 < CC; k0 += 32) {
        bf8 afr[2], bfr[4];
#pragma unroll
        for (int sr = 0; sr < 2; sr++)
            afr[sr] = *(const bf8*)&xb[((size_t)(b * NN + n0 + w * 32 + sr * 16 + l16)) * CC + k0 + quad * 8];
#pragma unroll
        for (int sc = 0; sc < 4; sc++)
            bfr[sc] = *(const bf8*)&Wc[(size_t)(sc * 16 + l16) * CC + k0 + quad * 8];
#pragma unroll
        for (int sr = 0; sr < 2; sr++)
#pragma unroll
            for (int sc = 0; sc < 4; sc++)
                acc[sr][sc] = mfma16(afr[sr], bfr[sc], acc[sr][sc]);
    }
#pragma unroll
    for (int sr = 0; sr < 2; sr++)
#pragma unroll
        for (int sc = 0; sc < 4; sc++) {
            int m = sc * 16 + l16;
            float bias = bc[m];
            bf4 p;
#pragma unroll
            for (int r = 0; r < 4; r++) {
                float val = acc[sr][sc][r] + bias;
                val = 1.0f / (1.0f + __expf(-val));
                p[r] = f2bf(val * (1.0f / 1024.0f));
            }
            *(bf4*)&cbmn[((size_t)(b * MM + m)) * NN + n0 + w * 32 + sr * 16 + quad * 4] = p;
        }
}

// ---------- K2: z[b,m,c] = sum_n c_bmn[b,m,n] * xt[b,c,n]   (LDS-free, fp32 out) ----------
__global__ __launch_bounds__(256) void k_z(const __bf16* __restrict__ cbmn,
        const __bf16* __restrict__ xt, float* __restrict__ z) {
    int c0 = blockIdx.x * 64, b = blockIdx.y;
    int t = threadIdx.x, w = t >> 6, l = t & 63, quad = l >> 4, l16 = l & 15;
    f4v acc[4];
#pragma unroll
    for (int j = 0; j < 4; j++) acc[j] = (f4v)0.0f;
    for (int n0 = 0; n0 < NN; n0 += 32) {
        bf8 afr = *(const bf8*)&cbmn[((size_t)(b * MM + w * 16 + l16)) * NN + n0 + quad * 8];
#pragma unroll
        for (int sc = 0; sc < 4; sc++) {
            bf8 bfr = *(const bf8*)&xt[((size_t)(b * CC + c0 + sc * 16 + l16)) * NN + n0 + quad * 8];
            acc[sc] = mfma16(afr, bfr, acc[sc]);
        }
    }
#pragma unroll
    for (int sc = 0; sc < 4; sc++) {
        int cc = c0 + sc * 16 + l16;
#pragma unroll
        for (int r = 0; r < 4; r++) {
            int m = w * 16 + quad * 4 + r;
            z[((size_t)(b * MM + m)) * CC + cc] = acc[sc][r];
        }
    }
}

// ---------- K2b: L2-normalize rows of z, write bf16 ----------
__global__ __launch_bounds__(256) void k_znorm(const float* __restrict__ z, __bf16* __restrict__ zb) {
    int w = threadIdx.x >> 6, l = threadIdx.x & 63;
    int row = blockIdx.x * 4 + w;
    const float* zr = &z[(size_t)row * CC];
    float v[12]; float ss = 0.f;
#pragma unroll
    for (int i = 0; i < 12; i++) { v[i] = zr[l + i * 64]; ss += v[i] * v[i]; }
#pragma unroll
    for (int off = 32; off; off >>= 1) ss += __shfl_xor(ss, off);
    float s = 1.0f / fmaxf(sqrtf(ss), 1e-12f);
    __bf16* zo = &zb[(size_t)row * CC];
#pragma unroll
    for (int i = 0; i < 12; i++) zo[l + i * 64] = f2bf(v[i] * s);
}

// ---------- K3: k = z@Wk^T+bk -> (b,h,m,d); v = z@Wv^T+bv -> TRANSPOSED (b,h,d,m) ----------
__global__ __launch_bounds__(256) void k_kv(const __bf16* __restrict__ zb,
        const __bf16* __restrict__ Wk, const float* __restrict__ bk,
        const __bf16* __restrict__ Wv, const float* __restrict__ bv,
        __bf16* __restrict__ kout, __bf16* __restrict__ vtout) {
    int ct = blockIdx.x, b = blockIdx.y, which = blockIdx.z;
    const __bf16* W = which ? Wv : Wk;
    const float* bias = which ? bv : bk;
    int t = threadIdx.x, w = t >> 6, l = t & 63, quad = l >> 4, l16 = l & 15;
    f4v acc[4][2];
#pragma unroll
    for (int i = 0; i < 4; i++) for (int j = 0; j < 2; j++) acc[i][j] = (f4v)0.0f;
    for (int k0 = 0; k0 < CC; k0 += 32) {
        bf8 afr[4], bfr[2];
#pragma unroll
        for (int sr = 0; sr < 4; sr++)
            afr[sr] = *(const bf8*)&zb[((size_t)(b * MM + sr * 16 + l16)) * CC + k0 + quad * 8];
#pragma unroll
        for (int sc = 0; sc < 2; sc++)
            bfr[sc] = *(const bf8*)&W[((size_t)(ct * 128 + w * 32 + sc * 16 + l16)) * CC + k0 + quad * 8];
#pragma unroll
        for (int sr = 0; sr < 4; sr++)
#pragma unroll
            for (int sc = 0; sc < 2; sc++)
                acc[sr][sc] = mfma16(afr[sr], bfr[sc], acc[sr][sc]);
    }
#pragma unroll
    for (int sr = 0; sr < 4; sr++)
#pragma unroll
        for (int sc = 0; sc < 2; sc++) {
            int col = ct * 128 + w * 32 + sc * 16 + l16;
            float bb = bias[col];
            int h = col >> 6, d = col & 63;
            if (which == 0) {
#pragma unroll
                for (int r = 0; r < 4; r++) {
                    int m = sr * 16 + quad * 4 + r;
                    kout[(((size_t)(b * HH + h)) * MM + m) * DD + d] = f2bf(acc[sr][sc][r] + bb);
                }
            } else {
                bf4 p;
#pragma unroll
                for (int r = 0; r < 4; r++) p[r] = f2bf(acc[sr][sc][r] + bb);
                *(bf4*)&vtout[(((size_t)(b * HH + h)) * DD + d) * MM + sr * 16 + quad * 4] = p;
            }
        }
}

// ---------- K4: q = xb @ Wq^T + bq -> (b,n,c) bf16  (128x128, global_load_lds) ----------
__global__ __launch_bounds__(256) void k_qproj(const __bf16* __restrict__ xb,
        const __bf16* __restrict__ Wq, const float* __restrict__ bq,
        __bf16* __restrict__ qb) {
    int jt = blockIdx.x;
    size_t arow0 = (size_t)blockIdx.y * 128;
    __shared__ __align__(16) __bf16 As[128 * 32];
    __shared__ __align__(16) __bf16 Bs[128 * 32];
    int t = threadIdx.x, w = t >> 6, l = t & 63, quad = l >> 4, l16 = l & 15;
    int wr = w & 1, wc = w >> 1;
    f4v acc[4][4];
#pragma unroll
    for (int i = 0; i < 4; i++) for (int j = 0; j < 4; j++) acc[i][j] = (f4v)0.0f;
    for (int k0 = 0; k0 < CC; k0 += 32) {
#pragma unroll
        for (int i = 0; i < 2; i++) {
            int row = i * 64 + w * 16 + (l >> 2), ch = l & 3;
            gl2lds16(&xb[(arow0 + row) * CC + k0 + ch * 8], &As[i * 2048 + w * 512]);
            gl2lds16(&Wq[((size_t)(jt * 128 + row)) * CC + k0 + ch * 8], &Bs[i * 2048 + w * 512]);
        }
        __syncthreads();
        bf8 afr[4], bfr[4];
#pragma unroll
        for (int sr = 0; sr < 4; sr++) afr[sr] = *(const bf8*)&As[(wr * 64 + sr * 16 + l16) * 32 + quad * 8];
#pragma unroll
        for (int sc = 0; sc < 4; sc++) bfr[sc] = *(const bf8*)&Bs[(wc * 64 + sc * 16 + l16) * 32 + quad * 8];
#pragma unroll
        for (int sr = 0; sr < 4; sr++)
#pragma unroll
            for (int sc = 0; sc < 4; sc++)
                acc[sr][sc] = mfma16(afr[sr], bfr[sc], acc[sr][sc]);
        __syncthreads();
    }
#pragma unroll
    for (int sc = 0; sc < 4; sc++) {
        int col = jt * 128 + wc * 64 + sc * 16 + l16;
        float bb = bq[col];
#pragma unroll
        for (int sr = 0; sr < 4; sr++)
#pragma unroll
            for (int r = 0; r < 4; r++) {
                size_t row = arow0 + wr * 64 + sr * 16 + quad * 4 + r;
                qb[row * CC + col] = f2bf(acc[sr][sc][r] + bb);
            }
    }
}

// ---------- K5: attention: s=q@k^T, softmax, o=p@v  (only LDS = P round-trip, no barriers) ----------
#define QS 72
__global__ __launch_bounds__(256) void k_attn(const __bf16* __restrict__ qb,
        const __bf16* __restrict__ kb, const __bf16* __restrict__ vt,
        __bf16* __restrict__ ob) {
    int n0 = blockIdx.x * 128, h = blockIdx.y, b = blockIdx.z;
    __shared__ __align__(16) __bf16 ps[128 * QS];
    int t = threadIdx.x, w = t >> 6, l = t & 63, quad = l >> 4, l16 = l & 15;
    size_t bh = (size_t)(b * HH + h);

    // phase 1: s = q @ k^T (K=64), all operands direct-global
    f4v sacc[2][4];
#pragma unroll
    for (int i = 0; i < 2; i++) for (int j = 0; j < 4; j++) sacc[i][j] = (f4v)0.0f;
#pragma unroll
    for (int kc = 0; kc < 2; kc++) {
        bf8 afr[2], bfr[4];
#pragma unroll
        for (int sr = 0; sr < 2; sr++)
            afr[sr] = *(const bf8*)&qb[((size_t)(b * NN + n0 + w * 32 + sr * 16 + l16)) * CC + h * 64 + kc * 32 + quad * 8];
#pragma unroll
        for (int sc = 0; sc < 4; sc++)
            bfr[sc] = *(const bf8*)&kb[(bh * MM + sc * 16 + l16) * DD + kc * 32 + quad * 8];
#pragma unroll
        for (int sr = 0; sr < 2; sr++)
#pragma unroll
            for (int sc = 0; sc < 4; sc++)
                sacc[sr][sc] = mfma16(afr[sr], bfr[sc], sacc[sr][sc]);
    }
    // softmax over m (64), rows are wave-private -> no __syncthreads needed
#pragma unroll
    for (int sr = 0; sr < 2; sr++) {
#pragma unroll
        for (int r = 0; r < 4; r++) {
            float mx = -1e30f;
#pragma unroll
            for (int sc = 0; sc < 4; sc++) mx = fmaxf(mx, sacc[sr][sc][r] * 0.125f);
#pragma unroll
            for (int off = 1; off < 16; off <<= 1) mx = fmaxf(mx, __shfl_xor(mx, off));
            float e[4]; float sum = 0.f;
#pragma unroll
            for (int sc = 0; sc < 4; sc++) { e[sc] = __expf(sacc[sr][sc][r] * 0.125f - mx); sum += e[sc]; }
#pragma unroll
            for (int off = 1; off < 16; off <<= 1) sum += __shfl_xor(sum, off);
            float inv = 1.0f / sum;
            int row = w * 32 + sr * 16 + quad * 4 + r;
#pragma unroll
            for (int sc = 0; sc < 4; sc++) ps[row * QS + sc * 16 + l16] = f2bf(e[sc] * inv);
        }
    }
    // phase 2: o = p @ v  (B = v^T direct-global)
    f4v oacc[2][4];
#pragma unroll
    for (int i = 0; i < 2; i++) for (int j = 0; j < 4; j++) oacc[i][j] = (f4v)0.0f;
#pragma unroll
    for (int kc = 0; kc < 2; kc++) {
        bf8 afr[2], bfr[4];
#pragma unroll
        for (int sr = 0; sr < 2; sr++)
            afr[sr] = *(const bf8*)&ps[(w * 32 + sr * 16 + l16) * QS + kc * 32 + quad * 8];
#pragma unroll
        for (int sc = 0; sc < 4; sc++)
            bfr[sc] = *(const bf8*)&vt[(bh * DD + sc * 16 + l16) * MM + kc * 32 + quad * 8];
#pragma unroll
        for (int sr = 0; sr < 2; sr++)
#pragma unroll
            for (int sc = 0; sc < 4; sc++)
                oacc[sr][sc] = mfma16(afr[sr], bfr[sc], oacc[sr][sc]);
    }
#pragma unroll
    for (int sr = 0; sr < 2; sr++)
#pragma unroll
        for (int sc = 0; sc < 4; sc++) {
            int d = sc * 16 + l16;
#pragma unroll
            for (int r = 0; r < 4; r++) {
                int row = n0 + w * 32 + sr * 16 + quad * 4 + r;
                ob[((size_t)(b * NN + row)) * CC + h * 64 + d] = f2bf(oacc[sr][sc][r]);
            }
        }
}

// ---------- K6: out = o @ Wp^T + bp  (fp32 out, 128x128, global_load_lds) ----------
__global__ __launch_bounds__(256) void k_oproj(const __bf16* __restrict__ ob,
        const __bf16* __restrict__ Wp, const float* __restrict__ bp,
        float* __restrict__ out) {
    int jt = blockIdx.x;
    size_t arow0 = (size_t)blockIdx.y * 128;
    __shared__ __align__(16) __bf16 As[128 * 32];
    __shared__ __align__(16) __bf16 Bs[128 * 32];
    int t = threadIdx.x, w = t >> 6, l = t & 63, quad = l >> 4, l16 = l & 15;
    int wr = w & 1, wc = w >> 1;
    f4v acc[4][4];
#pragma unroll
    for (int i = 0; i < 4; i++) for (int j = 0; j < 4; j++) acc[i][j] = (f4v)0.0f;
    for (int k0 = 0; k0 < CC; k0 += 32) {
#pragma unroll
        for (int i = 0; i < 2; i++) {
            int row = i * 64 + w * 16 + (l >> 2), ch = l & 3;
            gl2lds16(&ob[(arow0 + row) * CC + k0 + ch * 8], &As[i * 2048 + w * 512]);
            gl2lds16(&Wp[((size_t)(jt * 128 + row)) * CC + k0 + ch * 8], &Bs[i * 2048 + w * 512]);
        }
        __syncthreads();
        bf8 afr[4], bfr[4];
#pragma unroll
        for (int sr = 0; sr < 4; sr++) afr[sr] = *(const bf8*)&As[(wr * 64 + sr * 16 + l16) * 32 + quad * 8];
#pragma unroll
        for (int sc = 0; sc < 4; sc++) bfr[sc] = *(const bf8*)&Bs[(wc * 64 + sc * 16 + l16) * 32 + quad * 8];
#pragma unroll
        for (int sr = 0; sr < 4; sr++)
#pragma unroll
            for (int sc = 0; sc < 4; sc++)
                acc[sr][sc] = mfma16(afr[sr], bfr[sc], acc[sr][sc]);
        __syncthreads();
    }
#pragma unroll
    for (int sc = 0; sc < 4; sc++) {
        int col = jt * 128 + wc * 64 + sc * 16 + l16;
        float bb = bp[col];
#pragma unroll
        for (int sr = 0; sr < 4; sr++)
#pragma unroll
            for (int r = 0; r < 4; r++) {
                size_t row = arow0 + wr * 64 + sr * 16 + quad * 4 + r;
                out[row * CC + col] = acc[sr][sc][r] + bb;
            }
    }
}

extern "C" void kernel_launch(void* const* d_in, const int* in_sizes, int n_in,
                              void* d_out, int out_size, void* d_ws, size_t ws_size,
                              hipStream_t stream) {
    (void)in_sizes; (void)n_in; (void)out_size; (void)ws_size;
    const float* x  = (const float*)d_in[0];
    const float* Wc = (const float*)d_in[1];
    const float* bc = (const float*)d_in[2];
    const float* Wq = (const float*)d_in[3];
    const float* bq = (const float*)d_in[4];
    const float* Wk = (const float*)d_in[5];
    const float* bk = (const float*)d_in[6];
    const float* Wv = (const float*)d_in[7];
    const float* bv = (const float*)d_in[8];
    const float* Wp = (const float*)d_in[9];
    const float* bp = (const float*)d_in[10];
    float* out = (float*)d_out;

    char* ws = (char*)d_ws;
    size_t off = 0;
    auto alloc = [&](size_t bytes) { void* p = ws + off; off = (off + bytes + 255) & ~(size_t)255; return p; };
    __bf16* wc_b = (__bf16*)alloc((size_t)MM * CC * 2);
    __bf16* wq_b = (__bf16*)alloc((size_t)CC * CC * 2);
    __bf16* wk_b = (__bf16*)alloc((size_t)CC * CC * 2);
    __bf16* wv_b = (__bf16*)alloc((size_t)CC * CC * 2);
    __bf16* wp_b = (__bf16*)alloc((size_t)CC * CC * 2);
    __bf16* xb   = (__bf16*)alloc((size_t)BB * NN * CC * 2);
    __bf16* xt_o = (__bf16*)alloc((size_t)BB * NN * CC * 2);  // xt, later reused as o
    __bf16* q_b  = (__bf16*)alloc((size_t)BB * NN * CC * 2);
    __bf16* c_bmn= (__bf16*)alloc((size_t)BB * MM * NN * 2);
    float*  z_f  = (float*) alloc((size_t)BB * MM * CC * 4);
    __bf16* z_b  = (__bf16*)alloc((size_t)BB * MM * CC * 2);
    __bf16* k_b  = (__bf16*)alloc((size_t)BB * HH * MM * DD * 2);
    __bf16* v_t  = (__bf16*)alloc((size_t)BB * HH * MM * DD * 2);

    k_cvt4<<<(MM * CC / 4 + 255) / 256, 256, 0, stream>>>(Wc, wc_b, MM * CC / 4);
    k_cvt4<<<(CC * CC / 4 + 255) / 256, 256, 0, stream>>>(Wq, wq_b, CC * CC / 4);
    k_cvt4<<<(CC * CC / 4 + 255) / 256, 256, 0, stream>>>(Wk, wk_b, CC * CC / 4);
    k_cvt4<<<(CC * CC / 4 + 255) / 256, 256, 0, stream>>>(Wv, wv_b, CC * CC / 4);
    k_cvt4<<<(CC * CC / 4 + 255) / 256, 256, 0, stream>>>(Wp, wp_b, CC * CC / 4);

    k_cvtx<<<dim3(CC / 64, NN / 64, BB), 256, 0, stream>>>(x, xb, xt_o);
    k_cluster<<<dim3(NN / 128, BB), 256, 0, stream>>>(xb, wc_b, bc, c_bmn);
    k_z<<<dim3(CC / 64, BB), 256, 0, stream>>>(c_bmn, xt_o, z_f);
    k_znorm<<<(BB * MM) / 4, 256, 0, stream>>>(z_f, z_b);
    k_kv<<<dim3(CC / 128, BB, 2), 256, 0, stream>>>(z_b, wk_b, bk, wv_b, bv, k_b, v_t);
    k_qproj<<<dim3(CC / 128, (BB * NN) / 128), 256, 0, stream>>>(xb, wq_b, bq, q_b);
    k_attn<<<dim3(NN / 128, HH, BB), 256, 0, stream>>>(q_b, k_b, v_t, xt_o /* o reuses xt */);
    k_oproj<<<dim3(CC / 128, (BB * NN) / 128), 256, 0, stream>>>(xt_o, wp_b, bp, out);
}

// Round 4
// 480.746 us; speedup vs baseline: 1.0034x; 1.0008x over previous
//
#include <hip/hip_runtime.h>
#include <hip/hip_bf16.h>
#include <cstdint>

// ---- problem constants ----
#define BB 32
#define NN 1024
#define CC 768
#define MM 64
#define HH 12
#define DD 64

typedef float f4v __attribute__((ext_vector_type(4)));
typedef __bf16 bf8 __attribute__((ext_vector_type(8)));
typedef __bf16 bf4 __attribute__((ext_vector_type(4)));

__device__ __forceinline__ f4v mfma16(bf8 a, bf8 b, f4v c) {
    return __builtin_amdgcn_mfma_f32_16x16x32_bf16(a, b, c, 0, 0, 0);
}
__device__ __forceinline__ __bf16 f2bf(float f) { return (__bf16)f; }

__device__ __forceinline__ void gl2lds16(const void* g, void* lds) {
    __builtin_amdgcn_global_load_lds((const __attribute__((address_space(1))) void*)g,
                                     (__attribute__((address_space(3))) void*)lds, 16, 0, 0);
}

// ---------- all weight fp32 -> bf16 in ONE launch ----------
__global__ __launch_bounds__(256) void k_cvtW(
        const float* __restrict__ Wc, const float* __restrict__ Wq,
        const float* __restrict__ Wk, const float* __restrict__ Wv,
        const float* __restrict__ Wp,
        __bf16* __restrict__ wc, __bf16* __restrict__ wq,
        __bf16* __restrict__ wk, __bf16* __restrict__ wv,
        __bf16* __restrict__ wp) {
    const float* in; __bf16* out; int n4;
    switch (blockIdx.y) {
        case 0: in = Wc; out = wc; n4 = MM * CC / 4; break;
        case 1: in = Wq; out = wq; n4 = CC * CC / 4; break;
        case 2: in = Wk; out = wk; n4 = CC * CC / 4; break;
        case 3: in = Wv; out = wv; n4 = CC * CC / 4; break;
        default: in = Wp; out = wp; n4 = CC * CC / 4; break;
    }
    int i = blockIdx.x * 256 + threadIdx.x;
    if (i < n4) {
        float4 v = *(const float4*)&in[i * 4];
        bf4 o; o[0] = f2bf(v.x); o[1] = f2bf(v.y); o[2] = f2bf(v.z); o[3] = f2bf(v.w);
        *(bf4*)&out[i * 4] = o;
    }
}

// ---------- K0: x -> xb (b,n,c) bf16  AND  xt (b,c,n) bf16 (tiled transpose, full-line stores) ----------
#define TS 80
__global__ __launch_bounds__(256) void k_cvtx(const float* __restrict__ x,
        __bf16* __restrict__ xb, __bf16* __restrict__ xt) {
    int c0 = blockIdx.x * 64, n0 = blockIdx.y * 64, b = blockIdx.z;
    __shared__ __align__(16) __bf16 tile[64 * TS];
    int t = threadIdx.x;
#pragma unroll
    for (int i = 0; i < 4; i++) {
        int idx = t + 256 * i, r = idx >> 4, cq = idx & 15;
        float4 v = *(const float4*)&x[((size_t)(b * NN + n0 + r)) * CC + c0 + cq * 4];
        __bf16* d = &tile[r * TS + cq * 4];
        d[0] = f2bf(v.x); d[1] = f2bf(v.y); d[2] = f2bf(v.z); d[3] = f2bf(v.w);
    }
    __syncthreads();
#pragma unroll
    for (int i = 0; i < 2; i++) {
        int idx = t + 256 * i, r = idx >> 3, ch = idx & 7;
        *(bf8*)&xb[((size_t)(b * NN + n0 + r)) * CC + c0 + ch * 8] = *(const bf8*)&tile[r * TS + ch * 8];
    }
    // xt: one full 128B line (64 n) per c-row
#pragma unroll
    for (int i = 0; i < 2; i++) {
        int idx = t + 256 * i, c = idx >> 3, ch = idx & 7;
        bf8 v;
#pragma unroll
        for (int j = 0; j < 8; j++) v[j] = tile[(ch * 8 + j) * TS + c];
        *(bf8*)&xt[((size_t)(b * CC + c0 + c)) * NN + n0 + ch * 8] = v;
    }
}

// ---------- K1: c_bmn[b,m,n] = sigmoid(x@Wc^T + bc)/N   (LDS-free) ----------
__global__ __launch_bounds__(256) void k_cluster(const __bf16* __restrict__ xb,
        const __bf16* __restrict__ Wc, const float* __restrict__ bc,
        __bf16* __restrict__ cbmn) {
    int n0 = blockIdx.x * 128, b = blockIdx.y;
    int t = threadIdx.x, w = t >> 6, l = t & 63, quad = l >> 4, l16 = l & 15;
    f4v acc[2][4];
#pragma unroll
    for (int i = 0; i < 2; i++) for (int j = 0; j < 4; j++) acc[i][j] = (f4v)0.0f;
    for (int k0 = 0; k0 < CC; k0 += 32) {
        bf8 afr[2], bfr[4];
#pragma unroll
        for (int sr = 0; sr < 2; sr++)
            afr[sr] = *(const bf8*)&xb[((size_t)(b * NN + n0 + w * 32 + sr * 16 + l16)) * CC + k0 + quad * 8];
#pragma unroll
        for (int sc = 0; sc < 4; sc++)
            bfr[sc] = *(const bf8*)&Wc[(size_t)(sc * 16 + l16) * CC + k0 + quad * 8];
#pragma unroll
        for (int sr = 0; sr < 2; sr++)
#pragma unroll
            for (int sc = 0; sc < 4; sc++)
                acc[sr][sc] = mfma16(afr[sr], bfr[sc], acc[sr][sc]);
    }
#pragma unroll
    for (int sr = 0; sr < 2; sr++)
#pragma unroll
        for (int sc = 0; sc < 4; sc++) {
            int m = sc * 16 + l16;
            float bias = bc[m];
            bf4 p;
#pragma unroll
            for (int r = 0; r < 4; r++) {
                float val = acc[sr][sc][r] + bias;
                val = 1.0f / (1.0f + __expf(-val));
                p[r] = f2bf(val * (1.0f / 1024.0f));
            }
            *(bf4*)&cbmn[((size_t)(b * MM + m)) * NN + n0 + w * 32 + sr * 16 + quad * 4] = p;
        }
}

// ---------- K2: z[b,m,c] = sum_n c_bmn[b,m,n] * xt[b,c,n]   (LDS-free, fp32 out) ----------
__global__ __launch_bounds__(256) void k_z(const __bf16* __restrict__ cbmn,
        const __bf16* __restrict__ xt, float* __restrict__ z) {
    int c0 = blockIdx.x * 64, b = blockIdx.y;
    int t = threadIdx.x, w = t >> 6, l = t & 63, quad = l >> 4, l16 = l & 15;
    f4v acc[4];
#pragma unroll
    for (int j = 0; j < 4; j++) acc[j] = (f4v)0.0f;
    for (int n0 = 0; n0 < NN; n0 += 32) {
        bf8 afr = *(const bf8*)&cbmn[((size_t)(b * MM + w * 16 + l16)) * NN + n0 + quad * 8];
#pragma unroll
        for (int sc = 0; sc < 4; sc++) {
            bf8 bfr = *(const bf8*)&xt[((size_t)(b * CC + c0 + sc * 16 + l16)) * NN + n0 + quad * 8];
            acc[sc] = mfma16(afr, bfr, acc[sc]);
        }
    }
#pragma unroll
    for (int sc = 0; sc < 4; sc++) {
        int cc = c0 + sc * 16 + l16;
#pragma unroll
        for (int r = 0; r < 4; r++) {
            int m = w * 16 + quad * 4 + r;
            z[((size_t)(b * MM + m)) * CC + cc] = acc[sc][r];
        }
    }
}

// ---------- K2b: L2-normalize rows of z, write bf16 ----------
__global__ __launch_bounds__(256) void k_znorm(const float* __restrict__ z, __bf16* __restrict__ zb) {
    int w = threadIdx.x >> 6, l = threadIdx.x & 63;
    int row = blockIdx.x * 4 + w;
    const float* zr = &z[(size_t)row * CC];
    float v[12]; float ss = 0.f;
#pragma unroll
    for (int i = 0; i < 12; i++) { v[i] = zr[l + i * 64]; ss += v[i] * v[i]; }
#pragma unroll
    for (int off = 32; off; off >>= 1) ss += __shfl_xor(ss, off);
    float s = 1.0f / fmaxf(sqrtf(ss), 1e-12f);
    __bf16* zo = &zb[(size_t)row * CC];
#pragma unroll
    for (int i = 0; i < 12; i++) zo[l + i * 64] = f2bf(v[i] * s);
}

// ---------- K3: k = z@Wk^T+bk -> (b,h,m,d); v = z@Wv^T+bv -> TRANSPOSED (b,h,d,m) ----------
__global__ __launch_bounds__(256) void k_kv(const __bf16* __restrict__ zb,
        const __bf16* __restrict__ Wk, const float* __restrict__ bk,
        const __bf16* __restrict__ Wv, const float* __restrict__ bv,
        __bf16* __restrict__ kout, __bf16* __restrict__ vtout) {
    int ct = blockIdx.x, b = blockIdx.y, which = blockIdx.z;
    const __bf16* W = which ? Wv : Wk;
    const float* bias = which ? bv : bk;
    int t = threadIdx.x, w = t >> 6, l = t & 63, quad = l >> 4, l16 = l & 15;
    f4v acc[4][2];
#pragma unroll
    for (int i = 0; i < 4; i++) for (int j = 0; j < 2; j++) acc[i][j] = (f4v)0.0f;
    for (int k0 = 0; k0 < CC; k0 += 32) {
        bf8 afr[4], bfr[2];
#pragma unroll
        for (int sr = 0; sr < 4; sr++)
            afr[sr] = *(const bf8*)&zb[((size_t)(b * MM + sr * 16 + l16)) * CC + k0 + quad * 8];
#pragma unroll
        for (int sc = 0; sc < 2; sc++)
            bfr[sc] = *(const bf8*)&W[((size_t)(ct * 128 + w * 32 + sc * 16 + l16)) * CC + k0 + quad * 8];
#pragma unroll
        for (int sr = 0; sr < 4; sr++)
#pragma unroll
            for (int sc = 0; sc < 2; sc++)
                acc[sr][sc] = mfma16(afr[sr], bfr[sc], acc[sr][sc]);
    }
#pragma unroll
    for (int sr = 0; sr < 4; sr++)
#pragma unroll
        for (int sc = 0; sc < 2; sc++) {
            int col = ct * 128 + w * 32 + sc * 16 + l16;
            float bb = bias[col];
            int h = col >> 6, d = col & 63;
            if (which == 0) {
#pragma unroll
                for (int r = 0; r < 4; r++) {
                    int m = sr * 16 + quad * 4 + r;
                    kout[(((size_t)(b * HH + h)) * MM + m) * DD + d] = f2bf(acc[sr][sc][r] + bb);
                }
            } else {
                bf4 p;
#pragma unroll
                for (int r = 0; r < 4; r++) p[r] = f2bf(acc[sr][sc][r] + bb);
                *(bf4*)&vtout[(((size_t)(b * HH + h)) * DD + d) * MM + sr * 16 + quad * 4] = p;
            }
        }
}

// ---------- K4: q = xb @ Wq^T + bq -> (b,n,c) bf16  (128x128, LDS-transpose full-line epilogue) ----------
__global__ __launch_bounds__(256) void k_qproj(const __bf16* __restrict__ xb,
        const __bf16* __restrict__ Wq, const float* __restrict__ bq,
        __bf16* __restrict__ qb) {
    int jt = blockIdx.x;
    size_t arow0 = (size_t)blockIdx.y * 128;
    __shared__ __align__(16) __bf16 smem[2 * 128 * 32];   // As | Bs, reused as epilogue buf
    __bf16* As = smem;
    __bf16* Bs = smem + 128 * 32;
    int t = threadIdx.x, w = t >> 6, l = t & 63, quad = l >> 4, l16 = l & 15;
    int wr = w & 1, wc = w >> 1;
    f4v acc[4][4];
#pragma unroll
    for (int i = 0; i < 4; i++) for (int j = 0; j < 4; j++) acc[i][j] = (f4v)0.0f;
    for (int k0 = 0; k0 < CC; k0 += 32) {
#pragma unroll
        for (int i = 0; i < 2; i++) {
            int row = i * 64 + w * 16 + (l >> 2), ch = l & 3;
            gl2lds16(&xb[(arow0 + row) * CC + k0 + ch * 8], &As[i * 2048 + w * 512]);
            gl2lds16(&Wq[((size_t)(jt * 128 + row)) * CC + k0 + ch * 8], &Bs[i * 2048 + w * 512]);
        }
        __syncthreads();
        bf8 afr[4], bfr[4];
#pragma unroll
        for (int sr = 0; sr < 4; sr++) afr[sr] = *(const bf8*)&As[(wr * 64 + sr * 16 + l16) * 32 + quad * 8];
#pragma unroll
        for (int sc = 0; sc < 4; sc++) bfr[sc] = *(const bf8*)&Bs[(wc * 64 + sc * 16 + l16) * 32 + quad * 8];
#pragma unroll
        for (int sr = 0; sr < 4; sr++)
#pragma unroll
            for (int sc = 0; sc < 4; sc++)
                acc[sr][sc] = mfma16(afr[sr], bfr[sc], acc[sr][sc]);
        __syncthreads();
    }
    // epilogue: per-wave 64x64 bf16 tile through LDS -> full-line bf8 stores
    __bf16* qe = smem;
    for (int pw = 0; pw < 4; pw++) {
        if (w == pw) {
#pragma unroll
            for (int sc = 0; sc < 4; sc++) {
                int col = jt * 128 + wc * 64 + sc * 16 + l16;
                float bb = bq[col];
#pragma unroll
                for (int sr = 0; sr < 4; sr++)
#pragma unroll
                    for (int r = 0; r < 4; r++)
                        qe[(sr * 16 + quad * 4 + r) * 64 + sc * 16 + l16] = f2bf(acc[sr][sc][r] + bb);
            }
        }
        __syncthreads();
        int wr_p = pw & 1, wc_p = pw >> 1;
#pragma unroll
        for (int i = 0; i < 2; i++) {
            int idx = t + 256 * i, row = idx >> 3, ch = idx & 7;
            *(bf8*)&qb[(arow0 + wr_p * 64 + row) * CC + jt * 128 + wc_p * 64 + ch * 8] =
                *(const bf8*)&qe[row * 64 + ch * 8];
        }
        __syncthreads();
    }
}

// ---------- K5: attention: s=q@k^T, softmax, o=p@v  (full-line o stores via ps) ----------
#define QS 72
__global__ __launch_bounds__(256) void k_attn(const __bf16* __restrict__ qb,
        const __bf16* __restrict__ kb, const __bf16* __restrict__ vt,
        __bf16* __restrict__ ob) {
    int n0 = blockIdx.x * 128, h = blockIdx.y, b = blockIdx.z;
    __shared__ __align__(16) __bf16 ps[128 * QS];
    int t = threadIdx.x, w = t >> 6, l = t & 63, quad = l >> 4, l16 = l & 15;
    size_t bh = (size_t)(b * HH + h);

    // phase 1: s = q @ k^T (K=64), operands direct-global
    f4v sacc[2][4];
#pragma unroll
    for (int i = 0; i < 2; i++) for (int j = 0; j < 4; j++) sacc[i][j] = (f4v)0.0f;
#pragma unroll
    for (int kc = 0; kc < 2; kc++) {
        bf8 afr[2], bfr[4];
#pragma unroll
        for (int sr = 0; sr < 2; sr++)
            afr[sr] = *(const bf8*)&qb[((size_t)(b * NN + n0 + w * 32 + sr * 16 + l16)) * CC + h * 64 + kc * 32 + quad * 8];
#pragma unroll
        for (int sc = 0; sc < 4; sc++)
            bfr[sc] = *(const bf8*)&kb[(bh * MM + sc * 16 + l16) * DD + kc * 32 + quad * 8];
#pragma unroll
        for (int sr = 0; sr < 2; sr++)
#pragma unroll
            for (int sc = 0; sc < 4; sc++)
                sacc[sr][sc] = mfma16(afr[sr], bfr[sc], sacc[sr][sc]);
    }
    // softmax over m (wave-private rows)
#pragma unroll
    for (int sr = 0; sr < 2; sr++) {
#pragma unroll
        for (int r = 0; r < 4; r++) {
            float mx = -1e30f;
#pragma unroll
            for (int sc = 0; sc < 4; sc++) mx = fmaxf(mx, sacc[sr][sc][r] * 0.125f);
#pragma unroll
            for (int off = 1; off < 16; off <<= 1) mx = fmaxf(mx, __shfl_xor(mx, off));
            float e[4]; float sum = 0.f;
#pragma unroll
            for (int sc = 0; sc < 4; sc++) { e[sc] = __expf(sacc[sr][sc][r] * 0.125f - mx); sum += e[sc]; }
#pragma unroll
            for (int off = 1; off < 16; off <<= 1) sum += __shfl_xor(sum, off);
            float inv = 1.0f / sum;
            int row = w * 32 + sr * 16 + quad * 4 + r;
#pragma unroll
            for (int sc = 0; sc < 4; sc++) ps[row * QS + sc * 16 + l16] = f2bf(e[sc] * inv);
        }
    }
    // phase 2: o = p @ v
    f4v oacc[2][4];
#pragma unroll
    for (int i = 0; i < 2; i++) for (int j = 0; j < 4; j++) oacc[i][j] = (f4v)0.0f;
#pragma unroll
    for (int kc = 0; kc < 2; kc++) {
        bf8 afr[2], bfr[4];
#pragma unroll
        for (int sr = 0; sr < 2; sr++)
            afr[sr] = *(const bf8*)&ps[(w * 32 + sr * 16 + l16) * QS + kc * 32 + quad * 8];
#pragma unroll
        for (int sc = 0; sc < 4; sc++)
            bfr[sc] = *(const bf8*)&vt[(bh * DD + sc * 16 + l16) * MM + kc * 32 + quad * 8];
#pragma unroll
        for (int sr = 0; sr < 2; sr++)
#pragma unroll
            for (int sc = 0; sc < 4; sc++)
                oacc[sr][sc] = mfma16(afr[sr], bfr[sc], oacc[sr][sc]);
    }
    // epilogue: o-tile (128x64) via ps -> full-line bf8 stores (wave-private rows, 1 barrier)
#pragma unroll
    for (int sr = 0; sr < 2; sr++)
#pragma unroll
        for (int sc = 0; sc < 4; sc++) {
            int row = w * 32 + sr * 16;
#pragma unroll
            for (int r = 0; r < 4; r++)
                ps[(row + quad * 4 + r) * QS + sc * 16 + l16] = f2bf(oacc[sr][sc][r]);
        }
    __syncthreads();
#pragma unroll
    for (int i = 0; i < 4; i++) {
        int idx = t + 256 * i, row = idx >> 3, ch = idx & 7;
        *(bf8*)&ob[((size_t)(b * NN + n0 + row)) * CC + h * 64 + ch * 8] = *(const bf8*)&ps[row * QS + ch * 8];
    }
}

// ---------- K6: out = o @ Wp^T + bp  (fp32 out, LDS-transpose full-line epilogue) ----------
__global__ __launch_bounds__(256) void k_oproj(const __bf16* __restrict__ ob,
        const __bf16* __restrict__ Wp, const float* __restrict__ bp,
        float* __restrict__ out) {
    int jt = blockIdx.x;
    size_t arow0 = (size_t)blockIdx.y * 128;
    __shared__ __align__(16) __bf16 smem[2 * 128 * 32];   // As | Bs, reused as fp32 epilogue buf
    __bf16* As = smem;
    __bf16* Bs = smem + 128 * 32;
    int t = threadIdx.x, w = t >> 6, l = t & 63, quad = l >> 4, l16 = l & 15;
    int wr = w & 1, wc = w >> 1;
    f4v acc[4][4];
#pragma unroll
    for (int i = 0; i < 4; i++) for (int j = 0; j < 4; j++) acc[i][j] = (f4v)0.0f;
    for (int k0 = 0; k0 < CC; k0 += 32) {
#pragma unroll
        for (int i = 0; i < 2; i++) {
            int row = i * 64 + w * 16 + (l >> 2), ch = l & 3;
            gl2lds16(&ob[(arow0 + row) * CC + k0 + ch * 8], &As[i * 2048 + w * 512]);
            gl2lds16(&Wp[((size_t)(jt * 128 + row)) * CC + k0 + ch * 8], &Bs[i * 2048 + w * 512]);
        }
        __syncthreads();
        bf8 afr[4], bfr[4];
#pragma unroll
        for (int sr = 0; sr < 4; sr++) afr[sr] = *(const bf8*)&As[(wr * 64 + sr * 16 + l16) * 32 + quad * 8];
#pragma unroll
        for (int sc = 0; sc < 4; sc++) bfr[sc] = *(const bf8*)&Bs[(wc * 64 + sc * 16 + l16) * 32 + quad * 8];
#pragma unroll
        for (int sr = 0; sr < 4; sr++)
#pragma unroll
            for (int sc = 0; sc < 4; sc++)
                acc[sr][sc] = mfma16(afr[sr], bfr[sc], acc[sr][sc]);
        __syncthreads();
    }
    // epilogue: per-wave 64x64 fp32 tile through LDS (16 KB) -> full-line float4 stores
    float* eb = (float*)smem;
    for (int pw = 0; pw < 4; pw++) {
        if (w == pw) {
#pragma unroll
            for (int sc = 0; sc < 4; sc++) {
                int col = jt * 128 + wc * 64 + sc * 16 + l16;
                float bb = bp[col];
#pragma unroll
                for (int sr = 0; sr < 4; sr++)
#pragma unroll
                    for (int r = 0; r < 4; r++)
                        eb[(sr * 16 + quad * 4 + r) * 64 + sc * 16 + l16] = acc[sr][sc][r] + bb;
            }
        }
        __syncthreads();
        int wr_p = pw & 1, wc_p = pw >> 1;
#pragma unroll
        for (int i = 0; i < 4; i++) {
            int idx = t + 256 * i, row = idx >> 4, c4 = idx & 15;
            float4 v = ((const float4*)eb)[idx];
            *(float4*)&out[(arow0 + wr_p * 64 + row) * CC + jt * 128 + wc_p * 64 + c4 * 4] = v;
        }
        __syncthreads();
    }
}

extern "C" void kernel_launch(void* const* d_in, const int* in_sizes, int n_in,
                              void* d_out, int out_size, void* d_ws, size_t ws_size,
                              hipStream_t stream) {
    (void)in_sizes; (void)n_in; (void)out_size; (void)ws_size;
    const float* x  = (const float*)d_in[0];
    const float* Wc = (const float*)d_in[1];
    const float* bc = (const float*)d_in[2];
    const float* Wq = (const float*)d_in[3];
    const float* bq = (const float*)d_in[4];
    const float* Wk = (const float*)d_in[5];
    const float* bk = (const float*)d_in[6];
    const float* Wv = (const float*)d_in[7];
    const float* bv = (const float*)d_in[8];
    const float* Wp = (const float*)d_in[9];
    const float* bp = (const float*)d_in[10];
    float* out = (float*)d_out;

    char* ws = (char*)d_ws;
    size_t off = 0;
    auto alloc = [&](size_t bytes) { void* p = ws + off; off = (off + bytes + 255) & ~(size_t)255; return p; };
    __bf16* wc_b = (__bf16*)alloc((size_t)MM * CC * 2);
    __bf16* wq_b = (__bf16*)alloc((size_t)CC * CC * 2);
    __bf16* wk_b = (__bf16*)alloc((size_t)CC * CC * 2);
    __bf16* wv_b = (__bf16*)alloc((size_t)CC * CC * 2);
    __bf16* wp_b = (__bf16*)alloc((size_t)CC * CC * 2);
    __bf16* xb   = (__bf16*)alloc((size_t)BB * NN * CC * 2);
    __bf16* xt_o = (__bf16*)alloc((size_t)BB * NN * CC * 2);  // xt, reused as o
    __bf16* q_b  = (__bf16*)alloc((size_t)BB * NN * CC * 2);
    __bf16* c_bmn= (__bf16*)alloc((size_t)BB * MM * NN * 2);
    float*  z_f  = (float*) alloc((size_t)BB * MM * CC * 4);
    __bf16* z_b  = (__bf16*)alloc((size_t)BB * MM * CC * 2);
    __bf16* k_b  = (__bf16*)alloc((size_t)BB * HH * MM * DD * 2);
    __bf16* v_t  = (__bf16*)alloc((size_t)BB * HH * MM * DD * 2);

    k_cvtW<<<dim3((CC * CC / 4 + 255) / 256, 5), 256, 0, stream>>>(
        Wc, Wq, Wk, Wv, Wp, wc_b, wq_b, wk_b, wv_b, wp_b);

    k_cvtx<<<dim3(CC / 64, NN / 64, BB), 256, 0, stream>>>(x, xb, xt_o);
    k_cluster<<<dim3(NN / 128, BB), 256, 0, stream>>>(xb, wc_b, bc, c_bmn);
    k_z<<<dim3(CC / 64, BB), 256, 0, stream>>>(c_bmn, xt_o, z_f);
    k_znorm<<<(BB * MM) / 4, 256, 0, stream>>>(z_f, z_b);
    k_kv<<<dim3(CC / 128, BB, 2), 256, 0, stream>>>(z_b, wk_b, bk, wv_b, bv, k_b, v_t);
    k_qproj<<<dim3(CC / 128, (BB * NN) / 128), 256, 0, stream>>>(xb, wq_b, bq, q_b);
    k_attn<<<dim3(NN / 128, HH, BB), 256, 0, stream>>>(q_b, k_b, v_t, xt_o /* o reuses xt */);
    k_oproj<<<dim3(CC / 128, (BB * NN) / 128), 256, 0, stream>>>(xt_o, wp_b, bp, out);
}